// Round 5
// baseline (403.384 us; speedup 1.0000x reference)
//
#include <hip/hip_runtime.h>
#include <hip/hip_bf16.h>

typedef unsigned u32;
typedef unsigned long long u64;
typedef unsigned short u16;
typedef __bf16 bf16x8 __attribute__((ext_vector_type(8)));
typedef float f32x4 __attribute__((ext_vector_type(4)));

// ---- problem shape (all f32) ----
// z: [4,256,32,32]  -> M=4096 rows (b*1024+hw), K=256
// codebook: [16384,256] -> N=16384
// image_encodings: [32,4,512] (256 KiB)  -- reused as scratch AFTER spherical
// prompts: [4,512]
// out: z_q f32[1048576] then dists f32[512]
// scratch layout in img buffer: best32 u32[4096]@0 | best64 u64[4096]@16384 | enorm f32[16384]@49152

#define DELTA 2.0f

__device__ __forceinline__ u32 fkey(float f) {
    u32 u = __float_as_uint(f);
    return (u & 0x80000000u) ? ~u : (u | 0x80000000u);
}
__device__ __forceinline__ float unfkey(u32 k) {
    return __uint_as_float((k & 0x80000000u) ? (k & 0x7fffffffu) : ~k);
}

// ---------- spherical distance loss (runs FIRST; consumes img before reuse) ----------
__global__ __launch_bounds__(512) void spherical(const float* __restrict__ img,
                                                 const float* __restrict__ prm,
                                                 float* __restrict__ dout) {
    const int k = threadIdx.x;  // 0..511
    float yv[4], yn2 = 0.f;
#pragma unroll
    for (int b = 0; b < 4; ++b) { yv[b] = prm[b * 512 + k]; yn2 += yv[b] * yv[b]; }
    float yn = fmaxf(sqrtf(yn2), 1e-12f);
#pragma unroll
    for (int b = 0; b < 4; ++b) yv[b] /= yn;
    float acc = 0.f;
    for (int i = 0; i < 32; ++i) {
        float xv[4], xn2 = 0.f;
#pragma unroll
        for (int b = 0; b < 4; ++b) { xv[b] = img[(i * 4 + b) * 512 + k]; xn2 += xv[b] * xv[b]; }
        float xn = fmaxf(sqrtf(xn2), 1e-12f);
        float d2 = 0.f;
#pragma unroll
        for (int b = 0; b < 4; ++b) { float t = xv[b] / xn - yv[b]; d2 += t * t; }
        float d = sqrtf(d2);
        float a = asinf(fminf(0.5f * d, 1.0f));
        acc += 2.0f * a * a;
    }
    dout[k] = acc * (1.0f / 32.0f);
}

// ---------- init scratch tables ----------
__global__ __launch_bounds__(256) void init_scratch(u32* __restrict__ best32,
                                                    u64* __restrict__ best64) {
    const int i = blockIdx.x * 256 + threadIdx.x;  // grid 16 -> 4096
    best32[i] = 0xFFFFFFFFu;
    best64[i] = ~0ull;
}

// ---------- codebook row norms (f32), one row per thread ----------
__global__ __launch_bounds__(256) void cb_norms(const float* __restrict__ cb,
                                                float* __restrict__ enorm) {
    const int row = blockIdx.x * 256 + threadIdx.x;  // grid 64 -> 16384
    const f32x4* p = (const f32x4*)(cb + (size_t)row * 256);
    float s0 = 0.f, s1 = 0.f, s2 = 0.f, s3 = 0.f;
#pragma unroll 8
    for (int j = 0; j < 64; ++j) {
        f32x4 v = p[j];
        s0 += v[0] * v[0]; s1 += v[1] * v[1];
        s2 += v[2] * v[2]; s3 += v[3] * v[3];
    }
    enorm[row] = (s0 + s1) + (s2 + s3);
}

// ---------- bf16-MFMA sweep: PASS 0 = approx row-min; PASS 1 = capture + f64 rescore ----------
// grid (64 m-tiles, 16 n-splits), 256 thr (4 waves). Wave covers col-tiles (it*4+w)*64.
template <int PASS>
__global__ __launch_bounds__(256) void sweep(const float* __restrict__ z,
                                             const float* __restrict__ cb,
                                             const float* __restrict__ enorm,
                                             u32* __restrict__ best32,
                                             u64* __restrict__ best64) {
    __shared__ u16 xa[64][264];     // x-tile bf16, [hw][c]
    __shared__ float sv[4][64];
    __shared__ float bestm[64];
    __shared__ int cnt[64];
    __shared__ int slots[64][12];

    const int tid = threadIdx.x;
    const int lane = tid & 63;
    const int w = tid >> 6;
    const int r16 = lane & 15;
    const int kg = lane >> 4;
    const int m0 = blockIdx.x * 64;
    const int bz = m0 >> 10;
    const int hw0 = m0 & 1023;
    const int nb = blockIdx.y * 1024;

    if (PASS == 1 && tid < 64) { bestm[tid] = unfkey(best32[m0 + tid]); cnt[tid] = 0; }

    // stage A: z[b][c][hw0..hw0+64) f32 -> xa[hw][c] bf16
    {
        const int c = tid >> 2, hwo = (tid & 3) * 16;
#pragma unroll
        for (int ch = 0; ch < 4; ++ch) {
            const float* src = z + (((size_t)(bz * 256 + ch * 64 + c)) << 10) + hw0 + hwo;
            float vv[16];
            *(f32x4*)&vv[0]  = *(const f32x4*)(src);
            *(f32x4*)&vv[4]  = *(const f32x4*)(src + 4);
            *(f32x4*)&vv[8]  = *(const f32x4*)(src + 8);
            *(f32x4*)&vv[12] = *(const f32x4*)(src + 12);
#pragma unroll
            for (int j = 0; j < 16; ++j) {
                __bf16 h = (__bf16)vv[j];
                xa[hwo + j][ch * 64 + c] = *(const u16*)&h;
            }
        }
    }
    __syncthreads();

    float bv[4][4];
#pragma unroll
    for (int mi = 0; mi < 4; ++mi)
#pragma unroll
        for (int r = 0; r < 4; ++r) bv[mi][r] = 3.4e38f;

#pragma unroll
    for (int it = 0; it < 4; ++it) {
        const int n0 = nb + (it * 4 + w) * 64;
        f32x4 acc[4][4];
#pragma unroll
        for (int mi = 0; mi < 4; ++mi)
#pragma unroll
            for (int ni = 0; ni < 4; ++ni) {
                f32x4 zz = {0.f, 0.f, 0.f, 0.f};
                acc[mi][ni] = zz;
            }
        const float* bp = cb + (((size_t)(n0 + r16)) << 8) + kg * 8;
#pragma unroll
        for (int k0 = 0; k0 < 8; ++k0) {
            bf16x8 fb[4];
#pragma unroll
            for (int ni = 0; ni < 4; ++ni) {
                const float* p = bp + (size_t)ni * 16 * 256 + k0 * 32;
                f32x4 lo = *(const f32x4*)p, hi = *(const f32x4*)(p + 4);
                bf16x8 f;
                f[0] = (__bf16)lo[0]; f[1] = (__bf16)lo[1];
                f[2] = (__bf16)lo[2]; f[3] = (__bf16)lo[3];
                f[4] = (__bf16)hi[0]; f[5] = (__bf16)hi[1];
                f[6] = (__bf16)hi[2]; f[7] = (__bf16)hi[3];
                fb[ni] = f;
            }
            bf16x8 fa[4];
#pragma unroll
            for (int mi = 0; mi < 4; ++mi)
                fa[mi] = *(const bf16x8*)&xa[r16 + mi * 16][kg * 8 + k0 * 32];
#pragma unroll
            for (int mi = 0; mi < 4; ++mi)
#pragma unroll
                for (int ni = 0; ni < 4; ++ni)
                    acc[mi][ni] = __builtin_amdgcn_mfma_f32_16x16x32_bf16(
                            fa[mi], fb[ni], acc[mi][ni], 0, 0, 0);
        }
#pragma unroll
        for (int ni = 0; ni < 4; ++ni) {
            const int n = n0 + ni * 16 + r16;
            const float en = enorm[n];
#pragma unroll
            for (int mi = 0; mi < 4; ++mi)
#pragma unroll
                for (int r = 0; r < 4; ++r) {
                    float s = en - 2.0f * acc[mi][ni][r];
                    if (PASS == 0) {
                        bv[mi][r] = fminf(bv[mi][r], s);
                    } else {
                        const int ml = mi * 16 + kg * 4 + r;  // D row = (lane>>4)*4+reg
                        if (s <= bestm[ml] + DELTA) {
                            int pos = atomicAdd(&cnt[ml], 1);
                            if (pos < 12) slots[ml][pos] = n;
                        }
                    }
                }
        }
    }

    if (PASS == 0) {
#pragma unroll
        for (int d = 1; d < 16; d <<= 1)
#pragma unroll
            for (int mi = 0; mi < 4; ++mi)
#pragma unroll
                for (int r = 0; r < 4; ++r)
                    bv[mi][r] = fminf(bv[mi][r], __shfl_xor(bv[mi][r], d));
        if (r16 == 0)
#pragma unroll
            for (int mi = 0; mi < 4; ++mi)
#pragma unroll
                for (int r = 0; r < 4; ++r)
                    sv[w][mi * 16 + kg * 4 + r] = bv[mi][r];
        __syncthreads();
        if (tid < 64) {
            float v = fminf(fminf(sv[0][tid], sv[1][tid]), fminf(sv[2][tid], sv[3][tid]));
            atomicMin(&best32[m0 + tid], fkey(v));
        }
    } else {
        __syncthreads();  // capture complete
        // exact f64 rescore of captured candidates, wave-cooperative round-robin
        int p = 0;
        for (int r = 0; r < 64; ++r) {
            int cn = cnt[r];
            if (cn > 12) cn = 12;
            for (int ci = 0; ci < cn; ++ci, ++p) {
                if ((p & 3) != w) continue;
                const int n = slots[r][ci];
                const int c0 = lane * 4;
                const f32x4 ev = *(const f32x4*)(cb + ((size_t)n << 8) + c0);
                double s = 0.0;
#pragma unroll
                for (int j = 0; j < 4; ++j) {
                    float xv = z[(((size_t)(bz * 256 + c0 + j)) << 10) + hw0 + r];
                    double dl = (double)xv - (double)ev[j];
                    s += dl * dl;
                }
#pragma unroll
                for (int d = 1; d < 64; d <<= 1) s += __shfl_xor(s, d);
                if (lane == 0) {
                    u64 key = (u64)__double_as_longlong(s);  // s >= 0: bits monotone
                    atomicMin(&best64[m0 + r], (key & ~0x3FFFull) | (u64)n);
                }
            }
        }
    }
}

// ---------- gather selected codebook rows (f32) into channel-first out ----------
// grid (16 hw-tiles, 4 b), 256 thr; two 128-channel halves staged in LDS.
__global__ __launch_bounds__(256) void vq_out(const u64* __restrict__ best64,
                                              const float* __restrict__ cb,
                                              float* __restrict__ out) {
    __shared__ float rows_l[64][133];
    __shared__ int idx_s[64];
    const int tid = threadIdx.x;
    const int hwt = blockIdx.x, b = blockIdx.y;
    const int m0 = b * 1024 + hwt * 64;
    if (tid < 64) idx_s[tid] = (int)(best64[m0 + tid] & 0x3FFFull);
    __syncthreads();
    const int lane = tid & 63, w = tid >> 6;
#pragma unroll
    for (int half = 0; half < 2; ++half) {
        const int row = tid >> 2, q = tid & 3;
        const float* src = cb + (((size_t)idx_s[row]) << 8) + half * 128 + q * 32;
#pragma unroll
        for (int j = 0; j < 8; ++j)
            *(f32x4*)&rows_l[row][q * 32 + j * 4] = *(const f32x4*)(src + j * 4);
        __syncthreads();
#pragma unroll
        for (int i = 0; i < 32; ++i) {
            const int c = half * 128 + w * 32 + i;
            out[(((size_t)(b * 256 + c)) << 10) + hwt * 64 + lane] = rows_l[lane][w * 32 + i];
        }
        __syncthreads();
    }
}

extern "C" void kernel_launch(void* const* d_in, const int* in_sizes, int n_in,
                              void* d_out, int out_size, void* d_ws, size_t ws_size,
                              hipStream_t stream) {
    const float* z   = (const float*)d_in[0];
    const float* cb  = (const float*)d_in[1];
    const float* img = (const float*)d_in[2];
    const float* prm = (const float*)d_in[3];
    float* out = (float*)d_out;

    // scratch inside the img input buffer (256 KiB); img is consumed by
    // spherical FIRST on this stream, and the harness restores inputs
    // from pristine copies before every launch.
    char* scr = (char*)d_in[2];
    u32* best32 = (u32*)scr;                  // 16 KiB
    u64* best64 = (u64*)(scr + 16384);        // 32 KiB
    float* enorm = (float*)(scr + 49152);     // 64 KiB

    spherical<<<1, 512, 0, stream>>>(img, prm, out + 1048576);
    init_scratch<<<16, 256, 0, stream>>>(best32, best64);
    cb_norms<<<64, 256, 0, stream>>>(cb, enorm);
    sweep<0><<<dim3(64, 16), 256, 0, stream>>>(z, cb, enorm, best32, best64);
    sweep<1><<<dim3(64, 16), 256, 0, stream>>>(z, cb, enorm, best32, best64);
    vq_out<<<dim3(16, 4), 256, 0, stream>>>(best64, cb, out);
}

// Round 6
// 304.450 us; speedup vs baseline: 1.3250x; 1.3250x over previous
//
#include <hip/hip_runtime.h>
#include <hip/hip_bf16.h>

typedef unsigned u32;
typedef unsigned long long u64;
typedef unsigned short u16;
typedef __bf16 bf16x8 __attribute__((ext_vector_type(8)));
typedef float f32x4 __attribute__((ext_vector_type(4)));
typedef u32 u32x4 __attribute__((ext_vector_type(4)));

// ---- problem shape (all f32) ----
// z: [4,256,32,32] -> M=4096 rows (b*1024+hw), K=256
// codebook: [16384,256] -> N=16384 ; 16 splits of 1024 cols
// out: z_q f32[1048576] then dists f32[512]
// scratch: cand slabs u32[4096][16][16] in d_out z_q region (exactly 4 MB);
//          img buffer (256 KiB, consumed first by spherical): bestn u32[4096]@0,
//          enorm f32[16384]@16384B.

#define DELTA 2.0f

__device__ __forceinline__ u32 fkey(float f) {
    u32 u = __float_as_uint(f);
    return (u & 0x80000000u) ? ~u : (u | 0x80000000u);
}
__device__ __forceinline__ float unfkey(u32 k) {
    return __uint_as_float((k & 0x80000000u) ? (k & 0x7fffffffu) : ~k);
}

// ---------- spherical distance loss (runs FIRST; consumes img before reuse) ----------
__global__ __launch_bounds__(512) void spherical(const float* __restrict__ img,
                                                 const float* __restrict__ prm,
                                                 float* __restrict__ dout) {
    const int k = threadIdx.x;  // 0..511
    float yv[4], yn2 = 0.f;
#pragma unroll
    for (int b = 0; b < 4; ++b) { yv[b] = prm[b * 512 + k]; yn2 += yv[b] * yv[b]; }
    float yn = fmaxf(sqrtf(yn2), 1e-12f);
#pragma unroll
    for (int b = 0; b < 4; ++b) yv[b] /= yn;
    float acc = 0.f;
    for (int i = 0; i < 32; ++i) {
        float xv[4], xn2 = 0.f;
#pragma unroll
        for (int b = 0; b < 4; ++b) { xv[b] = img[(i * 4 + b) * 512 + k]; xn2 += xv[b] * xv[b]; }
        float xn = fmaxf(sqrtf(xn2), 1e-12f);
        float d2 = 0.f;
#pragma unroll
        for (int b = 0; b < 4; ++b) { float t = xv[b] / xn - yv[b]; d2 += t * t; }
        float d = sqrtf(d2);
        float a = asinf(fminf(0.5f * d, 1.0f));
        acc += 2.0f * a * a;
    }
    dout[k] = acc * (1.0f / 32.0f);
}

// ---------- codebook row norms (f32), one row per thread ----------
__global__ __launch_bounds__(256) void cb_norms(const float* __restrict__ cb,
                                                float* __restrict__ enorm) {
    const int row = blockIdx.x * 256 + threadIdx.x;  // grid 64 -> 16384
    const f32x4* p = (const f32x4*)(cb + (size_t)row * 256);
    float s0 = 0.f, s1 = 0.f, s2 = 0.f, s3 = 0.f;
#pragma unroll 8
    for (int j = 0; j < 64; ++j) {
        f32x4 v = p[j];
        s0 += v[0] * v[0]; s1 += v[1] * v[1];
        s2 += v[2] * v[2]; s3 += v[3] * v[3];
    }
    enorm[row] = (s0 + s1) + (s2 + s3);
}

// ---------- single bf16-MFMA sweep with candidate capture ----------
// 1D grid 1024: split pinned to XCD via bid&7 (each XCD owns 2 splits = 2 MB
// codebook, L2-resident). Block = 64 rows x 1024 cols (one split), 4 waves.
__global__ __launch_bounds__(256) void sweep(const float* __restrict__ z,
                                             const float* __restrict__ cb,
                                             const float* __restrict__ enorm,
                                             u32* __restrict__ cand) {
    __shared__ u16 xa[64][264];     // x-tile bf16, [hw][c]
    __shared__ u64 rowbest[64];     // (fkey(min)<<32)|n  -> tie = lowest n
    __shared__ u32 rowmin[64];      // fkey(min), cheap read for capture
    __shared__ int cnt[64];
    __shared__ u32 candl[64][13];

    const int tid = threadIdx.x;
    const int lane = tid & 63;
    const int w = tid >> 6;
    const int r16 = lane & 15;
    const int kg = lane >> 4;
    const int bid = blockIdx.x;
    const int mtile = bid >> 4;                     // 0..63
    const int r4 = bid & 15;
    const int split = (r4 & 7) * 2 + (r4 >> 3);     // XCD (bid&7) owns {2k,2k+1}
    const int m0 = mtile * 64;
    const int bz = m0 >> 10;
    const int hw0 = m0 & 1023;
    const int nb = split * 1024;

    if (tid < 64) { rowbest[tid] = ~0ull; rowmin[tid] = 0xFFFFFFFFu; cnt[tid] = 0; }

    // stage A: z[b][c][hw0..hw0+64) f32 -> xa[hw][c] bf16
    {
        const int c = tid >> 2, hwo = (tid & 3) * 16;
#pragma unroll
        for (int ch = 0; ch < 4; ++ch) {
            const float* src = z + (((size_t)(bz * 256 + ch * 64 + c)) << 10) + hw0 + hwo;
            float vv[16];
            *(f32x4*)&vv[0]  = *(const f32x4*)(src);
            *(f32x4*)&vv[4]  = *(const f32x4*)(src + 4);
            *(f32x4*)&vv[8]  = *(const f32x4*)(src + 8);
            *(f32x4*)&vv[12] = *(const f32x4*)(src + 12);
#pragma unroll
            for (int j = 0; j < 16; ++j) {
                __bf16 h = (__bf16)vv[j];
                xa[hwo + j][ch * 64 + c] = *(const u16*)&h;
            }
        }
    }
    __syncthreads();

    for (int it = 0; it < 4; ++it) {
        const int n0 = nb + (it * 4 + w) * 64;
        f32x4 acc[4][4];
#pragma unroll
        for (int mi = 0; mi < 4; ++mi)
#pragma unroll
            for (int ni = 0; ni < 4; ++ni) {
                f32x4 zz = {0.f, 0.f, 0.f, 0.f};
                acc[mi][ni] = zz;
            }
        const float* bp = cb + (((size_t)(n0 + r16)) << 8) + kg * 8;
#pragma unroll
        for (int k0 = 0; k0 < 8; ++k0) {
            bf16x8 fb[4];
#pragma unroll
            for (int ni = 0; ni < 4; ++ni) {
                const float* p = bp + (size_t)ni * 16 * 256 + k0 * 32;
                f32x4 lo = *(const f32x4*)p, hi = *(const f32x4*)(p + 4);
                bf16x8 f;
                f[0] = (__bf16)lo[0]; f[1] = (__bf16)lo[1];
                f[2] = (__bf16)lo[2]; f[3] = (__bf16)lo[3];
                f[4] = (__bf16)hi[0]; f[5] = (__bf16)hi[1];
                f[6] = (__bf16)hi[2]; f[7] = (__bf16)hi[3];
                fb[ni] = f;
            }
            bf16x8 fa[4];
#pragma unroll
            for (int mi = 0; mi < 4; ++mi)
                fa[mi] = *(const bf16x8*)&xa[r16 + mi * 16][kg * 8 + k0 * 32];
#pragma unroll
            for (int mi = 0; mi < 4; ++mi)
#pragma unroll
                for (int ni = 0; ni < 4; ++ni)
                    acc[mi][ni] = __builtin_amdgcn_mfma_f32_16x16x32_bf16(
                            fa[mi], fb[ni], acc[mi][ni], 0, 0, 0);
        }
        // scores in-place: s = ||e||^2 - 2*dot  (row-constant ||x||^2 dropped)
#pragma unroll
        for (int ni = 0; ni < 4; ++ni) {
            const float en = enorm[n0 + ni * 16 + r16];
#pragma unroll
            for (int mi = 0; mi < 4; ++mi)
#pragma unroll
                for (int r = 0; r < 4; ++r)
                    acc[mi][ni][r] = en - 2.0f * acc[mi][ni][r];
        }
        // per-(mi,r): argmin over ni, then 16-lane argmin reduce -> LDS
#pragma unroll
        for (int mi = 0; mi < 4; ++mi)
#pragma unroll
            for (int r = 0; r < 4; ++r) {
                float v = acc[mi][0][r];
                int n = n0 + r16;
#pragma unroll
                for (int ni = 1; ni < 4; ++ni) {
                    float s = acc[mi][ni][r];
                    int nn = n0 + ni * 16 + r16;
                    if (s < v || (s == v && nn < n)) { v = s; n = nn; }
                }
#pragma unroll
                for (int d = 1; d < 16; d <<= 1) {
                    float ov = __shfl_xor(v, d);
                    int on = __shfl_xor(n, d);
                    if (ov < v || (ov == v && on < n)) { v = ov; n = on; }
                }
                if (r16 == 0) {
                    const int ml = mi * 16 + kg * 4 + r;   // D row = (lane>>4)*4+reg
                    atomicMin(&rowbest[ml], ((u64)fkey(v) << 32) | (u32)n);
                    atomicMin(&rowmin[ml], fkey(v));
                }
            }
        __syncthreads();   // all waves' mins for this it landed
        // capture: every score within DELTA of the (running) row min
#pragma unroll
        for (int mi = 0; mi < 4; ++mi)
#pragma unroll
            for (int r = 0; r < 4; ++r) {
                const int ml = mi * 16 + kg * 4 + r;
                const float thr = unfkey(rowmin[ml]) + DELTA;
#pragma unroll
                for (int ni = 0; ni < 4; ++ni) {
                    if (acc[mi][ni][r] <= thr) {
                        int pos = atomicAdd(&cnt[ml], 1);
                        if (pos < 13) candl[ml][pos] = (u32)(n0 + ni * 16 + r16);
                    }
                }
            }
    }
    __syncthreads();
    // write slab [64 rows][16 u32]: {minval_f32, min_n, cnt, cand0..cand12}
    {
        const int row_l = tid >> 2, q = tid & 3;
        u32x4 wv;
        if (q == 0) {
            u64 rb = rowbest[row_l];
            wv[0] = __float_as_uint(unfkey((u32)(rb >> 32)));
            wv[1] = (u32)rb;
            wv[2] = (u32)cnt[row_l];
            wv[3] = candl[row_l][0];
        } else {
            const int base = q * 4 - 3;  // 1, 5, 9
            wv[0] = candl[row_l][base];
            wv[1] = candl[row_l][base + 1];
            wv[2] = candl[row_l][base + 2];
            wv[3] = candl[row_l][base + 3];
        }
        u32* dst = cand + ((((size_t)(m0 + row_l)) * 16 + split) << 4) + q * 4;
        *(u32x4*)dst = wv;
    }
}

// ---------- finalize: exact f64 rescore of captured candidates ----------
// grid 1024 x 256: block = 4 rows, one wave per row.
__global__ __launch_bounds__(256) void finalize(const float* __restrict__ z,
                                                const float* __restrict__ cb,
                                                const u32* __restrict__ cand,
                                                u32* __restrict__ bestn) {
    __shared__ u32 slab[4][256];
    const int tid = threadIdx.x;
    const int w = tid >> 6, lane = tid & 63;
    const int row = blockIdx.x * 4 + w;
    const int bz = row >> 10, hw = row & 1023;

    *(u32x4*)&slab[w][lane * 4] = *(const u32x4*)(cand + (size_t)row * 256 + lane * 4);
    float xv[4];
#pragma unroll
    for (int j = 0; j < 4; ++j)
        xv[j] = z[(((size_t)(bz * 256 + lane * 4 + j)) << 10) + hw];
    __syncthreads();

    // global row min over the 16 splits (lane s*4 holds split s's minval word)
    float gm = ((lane & 3) == 0) ? __uint_as_float(slab[w][lane * 4]) : 3.4e38f;
#pragma unroll
    for (int d = 1; d < 64; d <<= 1) gm = fminf(gm, __shfl_xor(gm, d));

    double bs = 1e300;
    int bn = 0x7fffffff;
#define RESCORE(NV)                                                         \
    {                                                                       \
        const int n_ = (NV);                                                \
        f32x4 ev = *(const f32x4*)(cb + (((size_t)n_) << 8) + lane * 4);    \
        double t = 0.0;                                                     \
        _Pragma("unroll")                                                   \
        for (int j = 0; j < 4; ++j) {                                       \
            double dl = (double)xv[j] - (double)ev[j];                      \
            t += dl * dl;                                                   \
        }                                                                   \
        _Pragma("unroll")                                                   \
        for (int d = 1; d < 64; d <<= 1) t += __shfl_xor(t, d);             \
        if (t < bs || (t == bs && n_ < bn)) { bs = t; bn = n_; }            \
    }

    for (int s = 0; s < 16; ++s) {
        const float mvs = __uint_as_float(slab[w][s * 16]);
        if (mvs > gm + DELTA) continue;          // no candidate here can win
        RESCORE((int)slab[w][s * 16 + 1]);       // the split's bf16 argmin
        const u32 c = slab[w][s * 16 + 2];
        if (c > 13) {
            // capture overflow (astronomically rare): exact scan of this split
            for (int n = s * 1024; n < s * 1024 + 1024; ++n) RESCORE(n);
        } else {
            for (u32 ci = 0; ci < c; ++ci) RESCORE((int)slab[w][s * 16 + 3 + ci]);
        }
    }
#undef RESCORE
    if (lane == 0) bestn[row] = (u32)bn;
}

// ---------- gather selected codebook rows (f32) into channel-first out ----------
__global__ __launch_bounds__(256) void vq_out(const u32* __restrict__ bestn,
                                              const float* __restrict__ cb,
                                              float* __restrict__ out) {
    __shared__ float rows_l[64][133];
    __shared__ int idx_s[64];
    const int tid = threadIdx.x;
    const int hwt = blockIdx.x, b = blockIdx.y;
    const int m0 = b * 1024 + hwt * 64;
    if (tid < 64) idx_s[tid] = (int)bestn[m0 + tid];
    __syncthreads();
    const int lane = tid & 63, w = tid >> 6;
#pragma unroll
    for (int half = 0; half < 2; ++half) {
        const int row = tid >> 2, q = tid & 3;
        const float* src = cb + (((size_t)idx_s[row]) << 8) + half * 128 + q * 32;
#pragma unroll
        for (int j = 0; j < 8; ++j)
            *(f32x4*)&rows_l[row][q * 32 + j * 4] = *(const f32x4*)(src + j * 4);
        __syncthreads();
#pragma unroll
        for (int i = 0; i < 32; ++i) {
            const int c = half * 128 + w * 32 + i;
            out[(((size_t)(b * 256 + c)) << 10) + hwt * 64 + lane] = rows_l[lane][w * 32 + i];
        }
        __syncthreads();
    }
}

extern "C" void kernel_launch(void* const* d_in, const int* in_sizes, int n_in,
                              void* d_out, int out_size, void* d_ws, size_t ws_size,
                              hipStream_t stream) {
    const float* z   = (const float*)d_in[0];
    const float* cb  = (const float*)d_in[1];
    const float* img = (const float*)d_in[2];
    const float* prm = (const float*)d_in[3];
    float* out = (float*)d_out;

    // img buffer reused as small scratch after spherical consumes it.
    char* scr = (char*)d_in[2];
    u32* bestn = (u32*)scr;                   // 16 KiB
    float* enorm = (float*)(scr + 16384);     // 64 KiB
    // candidate slabs live in the z_q region of d_out (exactly 4 MiB),
    // fully overwritten by vq_out at the end.
    u32* cand = (u32*)d_out;

    spherical<<<1, 512, 0, stream>>>(img, prm, out + 1048576);
    cb_norms<<<64, 256, 0, stream>>>(cb, enorm);
    sweep<<<1024, 256, 0, stream>>>(z, cb, enorm, cand);
    finalize<<<1024, 256, 0, stream>>>(z, cb, cand, bestn);
    vq_out<<<dim3(16, 4), 256, 0, stream>>>(bestn, cb, out);
}